// Round 3
// baseline (263.402 us; speedup 1.0000x reference)
//
#include <hip/hip_runtime.h>
#include <hip/hip_cooperative_groups.h>
#include <math.h>

namespace cg = cooperative_groups;

#define NB 8192
#define ND 256
#define NBLK 512               // 32 i-tiles x 16 slices; all phases use this grid
#define MARGIN_F 0.3f
#define EPS_F 1e-6f
#define BIAS_F 512.0f          // v = |e_j|^2 + BIAS - 2*dot stays strictly positive
#define NEG_INIT 0x7F800000u   // +inf bits: neg-side sentinel (all real keys finite, positive)

typedef __attribute__((ext_vector_type(8))) short bf16x8;
typedef __attribute__((ext_vector_type(4))) float f32x4;
typedef __attribute__((ext_vector_type(4))) unsigned int u32x4;

__device__ __forceinline__ unsigned short f2bf(float x) {
    unsigned int u = __float_as_uint(x);
    return (unsigned short)((u + 0x7fffu + ((u >> 16) & 1u)) >> 16);
}

__device__ __forceinline__ void gld16(const void* g, void* l) {
    __builtin_amdgcn_global_load_lds(
        (const __attribute__((address_space(1))) void*)g,
        (__attribute__((address_space(3))) void*)l, 16, 0, 0);
}

// ================= phase 1: prep =================
// fp32 -> bf16 packed in MFMA-fragment order + biased sq norms + key/ticket init.
// Packed layout: row-group g=(row>>4): 8 subtiles (k>>5); within: lane=((k>>3)&3)*16+(row&15), 8 bf16.
// 512 blocks x 256 thr: block b preps rows b*16..+15 (each thread 2 packed units).
__device__ __forceinline__ void prep_phase(
        const float* __restrict__ emb, unsigned short* __restrict__ ehi,
        float* __restrict__ sqnb, unsigned int* __restrict__ pos_key,
        unsigned int* __restrict__ neg_key, unsigned int* __restrict__ ticket,
        int bid, int tid) {
    __shared__ float sm[4][16];
    const int w = tid >> 6, lane = tid & 63;
    float s = 0.0f;
#pragma unroll
    for (int h = 0; h < 2; ++h) {
        const int u = tid + h * 256;                    // packed unit 0..511
        const int row = bid * 16 + (u & 15);
        const int k = (u >> 6) * 32 + ((u >> 4) & 3) * 8;
        const float4 v0 = *reinterpret_cast<const float4*>(&emb[(size_t)row * ND + k]);
        const float4 v1 = *reinterpret_cast<const float4*>(&emb[(size_t)row * ND + k + 4]);
        ushort4 h0, h1;
        h0.x = f2bf(v0.x); h0.y = f2bf(v0.y); h0.z = f2bf(v0.z); h0.w = f2bf(v0.w);
        h1.x = f2bf(v1.x); h1.y = f2bf(v1.y); h1.z = f2bf(v1.z); h1.w = f2bf(v1.w);
        *reinterpret_cast<ushort4*>(&ehi[(size_t)bid * 4096 + u * 8])     = h0;
        *reinterpret_cast<ushort4*>(&ehi[(size_t)bid * 4096 + u * 8 + 4]) = h1;
        s += v0.x * v0.x + v0.y * v0.y + v0.z * v0.z + v0.w * v0.w
           + v1.x * v1.x + v1.y * v1.y + v1.z * v1.z + v1.w * v1.w;
    }
    // lanes {r,r+16,r+32,r+48} share row r
    s += __shfl_xor(s, 16, 64);
    s += __shfl_xor(s, 32, 64);
    if (lane < 16) sm[w][lane] = s;
    if (tid >= 32 && tid < 48) pos_key[bid * 16 + (tid - 32)] = 0u;
    if (tid >= 48 && tid < 64) neg_key[bid * 16 + (tid - 48)] = NEG_INIT;
    if (bid == 0 && tid == 0) atomicExch(ticket, 0u);
    __syncthreads();
    if (tid < 16)
        sqnb[bid * 16 + tid] = sm[0][tid] + sm[1][tid] + sm[2][tid] + sm[3][tid] + BIAS_F;
}

// ================= phase 2: pair + mine =================
template <bool DIAG>
__device__ __forceinline__ void mine_col(
        const f32x4 (&acc)[4], int lblj, unsigned encv, const int (&labr)[16],
        float (&pmax)[16], float (&nmin)[16], int colg, int wr_base, int q) {
    const float NEGF = __uint_as_float(NEG_INIT);
#pragma unroll
    for (int tr = 0; tr < 4; ++tr) {
#pragma unroll
        for (int reg = 0; reg < 4; ++reg) {
            const int r = tr * 4 + reg;
            const float keyf = __uint_as_float(
                (__float_as_uint(acc[tr][reg]) & 0xFFFFE000u) | encv);
            const bool same = (lblj == labr[r]);
            bool pc = same;
            if (DIAG) pc = same && (colg != (wr_base + tr * 16 + q * 4 + reg));
            pmax[r] = fmaxf(pmax[r], pc ? keyf : 0.0f);
            nmin[r] = fminf(nmin[r], same ? NEGF : keyf);
        }
    }
}

// Block tile 256 rows x 512 cols. 4 waves; wave = 64 rows (A resident, 128 VGPR, scaled -2).
// B: 64-col x 256-k chunks (32 KB) double-buffered, staged one j-step ahead; 1 barrier/jt.
// tc-outer: one acc column (16 VGPR) live; its mining interleaves under next column's MFMAs.
__device__ __forceinline__ void pair_phase(
        const unsigned short* __restrict__ ehi, const float* __restrict__ sqnb,
        const int* __restrict__ labels,
        unsigned int* __restrict__ pos_key, unsigned int* __restrict__ neg_key,
        int bid, int tid) {
    __shared__ __align__(16) short Bsh[2][16384];      // 2 x 32 KB
    __shared__ __align__(16) int lbl_i_s[256];
    __shared__ __align__(16) int lbl_j_s[512];
    __shared__ __align__(16) float sqj_s[512];

    const int w = tid >> 6, lane = tid & 63, q = lane >> 4, lx = lane & 15;
    const int slice = bid & 15;
    const int i_base = (bid >> 4) * 256;
    const int jcol0 = slice * 512;
    const int wr_base = i_base + w * 64;
    const int ga0 = wr_base >> 4;                      // wave's 4 A row-groups

    lbl_i_s[tid]        = labels[i_base + tid];
    lbl_j_s[tid]        = labels[jcol0 + tid];
    lbl_j_s[tid + 256]  = labels[jcol0 + 256 + tid];
    sqj_s[tid]          = sqnb[jcol0 + tid];
    sqj_s[tid + 256]    = sqnb[jcol0 + 256 + tid];

// stage j-step JT (64 cols x 256 k = 32 KB, contiguous in packed ehi) into Bsh[BUF]
#define STAGE(JT, BUF)                                                          \
    do {                                                                        \
        const unsigned short* _src = ehi + (size_t)(slice * 32 + (JT) * 4) * 4096; \
        _Pragma("unroll")                                                       \
        for (int p = 0; p < 8; ++p)                                             \
            gld16(_src + (size_t)(p * 256 + tid) * 8,                           \
                  &Bsh[BUF][(p * 256 + tid) * 8]);                              \
    } while (0)

    STAGE(0, 0);   // prologue stage; drained by the barrier below

    // A panel -> registers, scaled by -2 (bf16: flip sign, exp+1 — exact for normals)
    bf16x8 a[4][8];
#pragma unroll
    for (int tr = 0; tr < 4; ++tr)
#pragma unroll
        for (int kb = 0; kb < 8; ++kb) {
            union { u32x4 u; bf16x8 h; } cv;
            cv.u = *reinterpret_cast<const u32x4*>(
                &ehi[((size_t)(ga0 + tr) * 8 + kb) * 512 + lane * 8]);
            cv.u = (cv.u ^ 0x80008000u) + 0x00800080u;
            a[tr][kb] = cv.h;
        }

    float pmax[16], nmin[16];
    const float NEGF = __uint_as_float(NEG_INIT);
#pragma unroll
    for (int r = 0; r < 16; ++r) { pmax[r] = 0.0f; nmin[r] = NEGF; }

    __syncthreads();   // prologue gld16 drained; metadata LDS visible

    int labr[16];      // row labels for this lane's 16 C-rows (jt-invariant)
#pragma unroll
    for (int tr = 0; tr < 4; ++tr) {
        const int4 l = *reinterpret_cast<const int4*>(&lbl_i_s[w * 64 + tr * 16 + q * 4]);
        labr[tr * 4 + 0] = l.x; labr[tr * 4 + 1] = l.y;
        labr[tr * 4 + 2] = l.z; labr[tr * 4 + 3] = l.w;
    }

    int buf = 0;
#pragma unroll 1
    for (int jt = 0; jt < 8; ++jt) {
        if (jt < 7) {
            const int jn = jt + 1;
            STAGE(jn, buf ^ 1);                        // issue early; hidden under MFMAs
        }
        const bool diag = ((jcol0 + jt * 64) == wr_base);
        __builtin_amdgcn_s_setprio(1);
#pragma unroll
        for (int tc = 0; tc < 4; ++tc) {
            const int jcl = jt * 64 + tc * 16 + lx;    // local col 0..511
            const int lblj = lbl_j_s[jcl];
            const float sj = sqj_s[jcl];
            const unsigned encv = 8191u - (unsigned)(jcol0 + jcl);
            f32x4 acc[4];
#pragma unroll
            for (int tr = 0; tr < 4; ++tr) acc[tr] = (f32x4){sj, sj, sj, sj};
#pragma unroll
            for (int kb = 0; kb < 8; ++kb) {
                const bf16x8 bh = *reinterpret_cast<const bf16x8*>(
                    &Bsh[buf][(tc * 8 + kb) * 512 + lane * 8]);
#pragma unroll
                for (int tr = 0; tr < 4; ++tr)
                    acc[tr] = __builtin_amdgcn_mfma_f32_16x16x32_bf16(
                        a[tr][kb], bh, acc[tr], 0, 0, 0);
            }
            if (diag) mine_col<true >(acc, lblj, encv, labr, pmax, nmin, jcol0 + jcl, wr_base, q);
            else      mine_col<false>(acc, lblj, encv, labr, pmax, nmin, jcol0 + jcl, wr_base, q);
        }
        __builtin_amdgcn_s_setprio(0);
        __syncthreads();   // all waves done reading Bsh[buf]; next chunk staged+visible
        buf ^= 1;
    }
#undef STAGE

    // once-per-kernel cross-lane reduce (16-lane groups) + spread-address atomics
#pragma unroll
    for (int r = 0; r < 16; ++r) {
        float pm = pmax[r], nm = nmin[r];
#pragma unroll
        for (int mm = 1; mm < 16; mm <<= 1) {
            pm = fmaxf(pm, __shfl_xor(pm, mm, 64));
            nm = fminf(nm, __shfl_xor(nm, mm, 64));
        }
        if (lx == r) {
            const int row = wr_base + (r >> 2) * 16 + q * 4 + (r & 3);
            atomicMax(&pos_key[row], __float_as_uint(pm));
            atomicMin(&neg_key[row], __float_as_uint(nm));
        }
    }
}

// ================= phase 3: finalize + in-kernel reduction =================
// 16 anchors/block, one 16-lane group per anchor; ticket's last block reduces 512 partials.
__device__ __forceinline__ void final_phase(
        const float* __restrict__ emb,
        const unsigned int* __restrict__ pos_key, const unsigned int* __restrict__ neg_key,
        float* __restrict__ pbsum, float* __restrict__ pbcnt,
        unsigned int* __restrict__ ticket, float* __restrict__ out, int bid, int tid) {
    __shared__ float ssum[4], scnt[4];
    __shared__ float fs[4], fc[4];
    __shared__ unsigned int lastf;
    const int w = tid >> 6, lane = tid & 63;
    const int g = tid >> 4, l16 = tid & 15;
    const int a = bid * 16 + g;

    const unsigned pk = pos_key[a], nk = neg_key[a];
    const int pi = 8191 - (int)(pk & 8191u);
    const int ni = 8191 - (int)(nk & 8191u);
    const bool valid = (pk != 0u) && (nk != NEG_INIT);

    float sap = 0.0f, san = 0.0f;
#pragma unroll
    for (int c = 0; c < 4; ++c) {
        const int off = c * 64 + l16 * 4;
        const float4 av = *reinterpret_cast<const float4*>(&emb[(size_t)a  * ND + off]);
        const float4 pv = *reinterpret_cast<const float4*>(&emb[(size_t)pi * ND + off]);
        const float4 nv = *reinterpret_cast<const float4*>(&emb[(size_t)ni * ND + off]);
        const float d0 = av.x - pv.x + EPS_F, d1 = av.y - pv.y + EPS_F;
        const float d2 = av.z - pv.z + EPS_F, d3 = av.w - pv.w + EPS_F;
        sap += d0 * d0 + d1 * d1 + d2 * d2 + d3 * d3;
        const float e0 = av.x - nv.x + EPS_F, e1 = av.y - nv.y + EPS_F;
        const float e2 = av.z - nv.z + EPS_F, e3 = av.w - nv.w + EPS_F;
        san += e0 * e0 + e1 * e1 + e2 * e2 + e3 * e3;
    }
#pragma unroll
    for (int m = 1; m <= 8; m <<= 1) {
        sap += __shfl_xor(sap, m, 16);
        san += __shfl_xor(san, m, 16);
    }
    float per = 0.0f, cnt = 0.0f;
    if (l16 == 0 && valid) {
        per = fmaxf(sqrtf(sap) - sqrtf(san) + MARGIN_F, 0.0f);
        cnt = 1.0f;
    }
    per += __shfl_xor(per, 16, 64); cnt += __shfl_xor(cnt, 16, 64);
    per += __shfl_xor(per, 32, 64); cnt += __shfl_xor(cnt, 32, 64);
    if (lane == 0) { ssum[w] = per; scnt[w] = cnt; }
    __syncthreads();
    if (tid == 0) {
        pbsum[bid] = ssum[0] + ssum[1] + ssum[2] + ssum[3];
        pbcnt[bid] = scnt[0] + scnt[1] + scnt[2] + scnt[3];
        __threadfence();                               // partials visible device-wide
        lastf = (atomicAdd(ticket, 1u) == (unsigned)(NBLK - 1)) ? 1u : 0u;
    }
    __syncthreads();
    if (lastf != 0u) {                                 // uniform per block
        float s = atomicAdd(&pbsum[tid], 0.0f) + atomicAdd(&pbsum[tid + 256], 0.0f);
        float c = atomicAdd(&pbcnt[tid], 0.0f) + atomicAdd(&pbcnt[tid + 256], 0.0f);
#pragma unroll
        for (int m = 32; m; m >>= 1) { s += __shfl_down(s, m, 64); c += __shfl_down(c, m, 64); }
        if (lane == 0) { fs[w] = s; fc[w] = c; }
        __syncthreads();
        if (tid == 0) {
            const float S = fs[0] + fs[1] + fs[2] + fs[3];
            const float C = fc[0] + fc[1] + fc[2] + fc[3];
            out[0] = (C > 0.0f) ? (S / fmaxf(C, 1.0f)) : 0.0f;
        }
    }
}

// ================= kernels =================
__global__ __launch_bounds__(256, 2) void fused_k(
        const float* __restrict__ emb, const int* __restrict__ labels,
        unsigned short* __restrict__ ehi, float* __restrict__ sqnb,
        unsigned int* __restrict__ pos_key, unsigned int* __restrict__ neg_key,
        float* __restrict__ pbsum, float* __restrict__ pbcnt,
        unsigned int* __restrict__ ticket, float* __restrict__ out) {
    const int bid = blockIdx.x, tid = threadIdx.x;
    cg::grid_group grid = cg::this_grid();
    prep_phase(emb, ehi, sqnb, pos_key, neg_key, ticket, bid, tid);
    grid.sync();
    pair_phase(ehi, sqnb, labels, pos_key, neg_key, bid, tid);
    grid.sync();
    final_phase(emb, pos_key, neg_key, pbsum, pbcnt, ticket, out, bid, tid);
}

// fallback path (same phase code, kernel boundaries provide the sync/coherence)
__global__ __launch_bounds__(256) void prep_sk(
        const float* __restrict__ emb, unsigned short* __restrict__ ehi,
        float* __restrict__ sqnb, unsigned int* __restrict__ pos_key,
        unsigned int* __restrict__ neg_key, unsigned int* __restrict__ ticket) {
    prep_phase(emb, ehi, sqnb, pos_key, neg_key, ticket, blockIdx.x, threadIdx.x);
}
__global__ __launch_bounds__(256, 2) void pair_sk(
        const unsigned short* __restrict__ ehi, const float* __restrict__ sqnb,
        const int* __restrict__ labels,
        unsigned int* __restrict__ pos_key, unsigned int* __restrict__ neg_key) {
    pair_phase(ehi, sqnb, labels, pos_key, neg_key, blockIdx.x, threadIdx.x);
}
__global__ __launch_bounds__(256) void final_sk(
        const float* __restrict__ emb,
        const unsigned int* __restrict__ pos_key, const unsigned int* __restrict__ neg_key,
        float* __restrict__ pbsum, float* __restrict__ pbcnt,
        unsigned int* __restrict__ ticket, float* __restrict__ out) {
    final_phase(emb, pos_key, neg_key, pbsum, pbcnt, ticket, out, blockIdx.x, threadIdx.x);
}

extern "C" void kernel_launch(void* const* d_in, const int* in_sizes, int n_in,
                              void* d_out, int out_size, void* d_ws, size_t ws_size,
                              hipStream_t stream) {
    const float* emb = (const float*)d_in[0];
    const int* labels = (const int*)d_in[1];
    float* out = (float*)d_out;

    char* ws = (char*)d_ws;
    unsigned short* ehi = (unsigned short*)ws;                         // 4 MB packed
    float* sqnb = (float*)(ws + (size_t)NB * ND * 2);                  // 32 KB
    unsigned int* pos_key = (unsigned int*)(sqnb + NB);                // 32 KB
    unsigned int* neg_key = pos_key + NB;                              // 32 KB
    float* pbsum = (float*)(neg_key + NB);                             // 2 KB
    float* pbcnt = pbsum + NBLK;                                       // 2 KB
    unsigned int* ticket = (unsigned int*)(pbcnt + NBLK);              // 4 B

    void* args[] = {(void*)&emb, (void*)&labels, (void*)&ehi, (void*)&sqnb,
                    (void*)&pos_key, (void*)&neg_key, (void*)&pbsum, (void*)&pbcnt,
                    (void*)&ticket, (void*)&out};
    const hipError_t err = hipLaunchCooperativeKernel(
        (const void*)fused_k, dim3(NBLK), dim3(256), args, 0, stream);
    if (err != hipSuccess) {
        (void)hipGetLastError();   // clear sticky error; use 3-launch fallback
        hipLaunchKernelGGL(prep_sk, dim3(NBLK), dim3(256), 0, stream,
                           emb, ehi, sqnb, pos_key, neg_key, ticket);
        hipLaunchKernelGGL(pair_sk, dim3(NBLK), dim3(256), 0, stream,
                           ehi, sqnb, labels, pos_key, neg_key);
        hipLaunchKernelGGL(final_sk, dim3(NBLK), dim3(256), 0, stream,
                           emb, pos_key, neg_key, pbsum, pbcnt, ticket, out);
    }
}